// Round 9
// baseline (931.199 us; speedup 1.0000x reference)
//
#include <hip/hip_runtime.h>

typedef unsigned short u16;
typedef __bf16 bf16x8 __attribute__((ext_vector_type(8)));
typedef float f32x4 __attribute__((ext_vector_type(4)));
typedef float f32x2 __attribute__((ext_vector_type(2)));

#define DEV static __device__ __forceinline__

DEV u16 f2bf(float f) {
    unsigned int u = __builtin_bit_cast(unsigned int, f);
    u += 0x7FFFu + ((u >> 16) & 1u);
    return (u16)(u >> 16);
}

DEV bf16x8 frag_ld(const u16* p) {  // p must be 16B aligned
    return __builtin_bit_cast(bf16x8, *(const uint4*)p);
}

DEV float sigm(float x) { return 1.f / (1.f + __expf(-x)); }

DEV float blo(unsigned u) { return __builtin_bit_cast(float, u << 16); }
DEV float bhi(unsigned u) { return __builtin_bit_cast(float, u & 0xffff0000u); }
DEV f32x2 bf2(unsigned u) { return (f32x2){ blo(u), bhi(u) }; }

// stash[64][256] u16, 16B-unit XOR swizzle by row&7 (u16-index units: <<3)
DEV int sw(int row, int colu16) { return row * 256 + (colu16 ^ ((row & 7) << 3)); }

// global -> LDS direct (width 16B); lds dest must be wave-uniform base + lane*16
DEV void gld16(const u16* g, u16* l) {
    __builtin_amdgcn_global_load_lds(
        (const __attribute__((address_space(1))) unsigned int*)g,
        (__attribute__((address_space(3))) unsigned int*)l, 16, 0, 0);
}

// ---------------- kSetup: all one-time prep in a single dispatch ----------------
// blocks [0,512): slot init | [512,770): Wqk fold | [770,1346): 5 weight transposes
__global__ __launch_bounds__(256) void kSetup(
    const float* __restrict__ noise, const float* __restrict__ mean,
    const float* __restrict__ logv, float* __restrict__ slots,
    const float* __restrict__ Wq, const float* __restrict__ Wk,
    const float* __restrict__ bq, const float* __restrict__ bk,
    float* __restrict__ Wqk, float* __restrict__ wbc,
    const float* __restrict__ Wv,  float* __restrict__ WvT,
    const float* __restrict__ Wih, float* __restrict__ WihT,
    const float* __restrict__ Whh, float* __restrict__ WhhT,
    const float* __restrict__ W1,  float* __restrict__ W1T,
    const float* __restrict__ W2,  float* __restrict__ W2T)
{
    __shared__ float tile[32][33];
    const int bid = blockIdx.x, t = threadIdx.x;
    if (bid < 512) {
        const int id = bid * 256 + t;
        const int d = id & 255;
        slots[id] = mean[d] + __expf(logv[d]) * noise[id];
        return;
    }
    if (bid < 770) {
        const int a = bid - 512, e = t;
        if (a < 256) {
            float acc = 0.f;
            for (int d = 0; d < 256; ++d) acc += Wq[(size_t)d * 256 + a] * Wk[(size_t)d * 256 + e];
            Wqk[(size_t)a * 256 + e] = acc;
        } else if (a == 256) {
            float acc = 0.f;
            for (int d = 0; d < 256; ++d) acc += bq[d] * Wk[(size_t)d * 256 + e];
            wbc[e] = acc;
        } else {
            float acc = 0.f;
            for (int d = 0; d < 256; ++d) acc += Wq[(size_t)d * 256 + e] * bk[d];
            wbc[256 + e] = acc;
            if (e == 0) {
                float c0 = 0.f;
                for (int d = 0; d < 256; ++d) c0 += bq[d] * bk[d];
                wbc[512] = c0;
            }
        }
        return;
    }
    const int rb = bid - 770;
    const float* in; float* outp; int R, k;
    if (rb < 64)       { in = Wv;  outp = WvT;  R = 256; k = rb; }
    else if (rb < 256) { in = Wih; outp = WihT; R = 768; k = rb - 64; }
    else if (rb < 448) { in = Whh; outp = WhhT; R = 768; k = rb - 256; }
    else if (rb < 512) { in = W1;  outp = W1T;  R = 256; k = rb - 448; }
    else               { in = W2;  outp = W2T;  R = 256; k = rb - 512; }
    const int bx = k & 7, by = k >> 3;
    const int tx = t & 31, ty = t >> 5;
    const int c0 = bx * 32, r0 = by * 32;
    #pragma unroll
    for (int i = 0; i < 4; ++i)
        tile[ty + i * 8][tx] = in[(size_t)(r0 + ty + i * 8) * 256 + c0 + tx];
    __syncthreads();
    #pragma unroll
    for (int i = 0; i < 4; ++i)
        outp[(size_t)(c0 + ty + i * 8) * R + r0 + tx] = tile[tx][ty + i * 8];
}

// ---------------- kSn: LN(slots) -> qk = SCALE*(sn@Wqk + bqk) bf16; qc ----------------
__global__ __launch_bounds__(256) void kSn(
    const float* __restrict__ slots, const float* __restrict__ gs, const float* __restrict__ bs,
    const float* __restrict__ Wqk, const float* __restrict__ wbc,
    u16* __restrict__ qo, float* __restrict__ qc)
{
    __shared__ float SN[8][256];
    __shared__ float red2[4][8][64];
    const int t = threadIdx.x;
    const int b = blockIdx.y, seg = blockIdx.x;
    const int w = t >> 6, lane = t & 63;
    #pragma unroll
    for (int rr = 0; rr < 2; ++rr) {
        const int r = w * 2 + rr;
        const int c = lane * 4;
        const float4 x = *(const float4*)(slots + ((size_t)b * 8 + r) * 256 + c);
        float s1 = x.x + x.y + x.z + x.w;
        float s2 = x.x * x.x + x.y * x.y + x.z * x.z + x.w * x.w;
        #pragma unroll
        for (int o = 32; o > 0; o >>= 1) { s1 += __shfl_xor(s1, o); s2 += __shfl_xor(s2, o); }
        const float mu = s1 * (1.f / 256.f);
        const float rs = rsqrtf(s2 * (1.f / 256.f) - mu * mu + 1e-5f);
        const float4 g4 = *(const float4*)(gs + c);
        const float4 b4 = *(const float4*)(bs + c);
        SN[r][c + 0] = (x.x - mu) * rs * g4.x + b4.x;
        SN[r][c + 1] = (x.y - mu) * rs * g4.y + b4.y;
        SN[r][c + 2] = (x.z - mu) * rs * g4.z + b4.z;
        SN[r][c + 3] = (x.w - mu) * rs * g4.w + b4.w;
    }
    __syncthreads();
    const int c = seg * 64 + (t & 63);
    const int p = t >> 6;
    float acc[8] = {};
    #pragma unroll 4
    for (int d = p * 64; d < p * 64 + 64; ++d) {
        const float wq = Wqk[(size_t)d * 256 + c];
        #pragma unroll
        for (int r = 0; r < 8; ++r) acc[r] += wq * SN[r][d];
    }
    #pragma unroll
    for (int r = 0; r < 8; ++r) red2[p][r][t & 63] = acc[r];
    __syncthreads();
    const float bb = wbc[c];
    #pragma unroll
    for (int rr = t >> 6; rr < 8; rr += 4) {
        const float s = red2[0][rr][t & 63] + red2[1][rr][t & 63]
                      + red2[2][rr][t & 63] + red2[3][rr][t & 63];
        qo[((size_t)b * 16 + rr) * 256 + c] = f2bf((s + bb) * 0.0625f);
    }
    if (seg == 0) {
        const int r = t >> 5, l = t & 31;
        float a = 0.f;
        #pragma unroll
        for (int d8 = 0; d8 < 8; ++d8) a += SN[r][l * 8 + d8] * wbc[256 + l * 8 + d8];
        #pragma unroll
        for (int o = 16; o > 0; o >>= 1) a += __shfl_xor(a, o);
        if (l == 0) qc[(size_t)b * 8 + r] = 0.0625f * (a + wbc[512]);
    }
}

// ---------------- kF: [it0 fused LN] + dots -> softmax -> us (round-6 structure) ----------
// ONLY change vs verified round-6 kernel: FUSE=0 staging uses global_load_lds (16B,
// contiguous 1KB/wave/instr, no VGPR round-trip) with source pre-swizzled so that the
// linear LDS dest matches sw(); dots B-frags then read from the stash.
template<int FUSE>
__global__ __launch_bounds__(256, 3) void kF(
    const float* __restrict__ X,      // raw inputs f32 (FUSE only)
    const float* __restrict__ gin, const float* __restrict__ bin,
    const u16* __restrict__ Q,        // qk_s [B,16,256] bf16 (rows 8..15 unused)
    const float* __restrict__ qcg,    // [B,8]
    u16* __restrict__ XN,             // [B,4096,256] bf16 (written when FUSE)
    float* __restrict__ attn_out,
    float* __restrict__ part,         // [64][64][8][256] f32 (per-wave partials)
    float* __restrict__ part2,        // [64][64][8]      f32 (attn row-sums)
    int write_attn)
{
    __shared__ __align__(16) u16 stash[64 * 256];   // 32 KB, XOR-swizzled, wave-private rows
    __shared__ __align__(16) float att32[64][8];    // attn f32 [row][slot], wave-private rows
    const int tid = threadIdx.x;
    const int w = tid >> 6, lane = tid & 63;
    const int quad = lane >> 4, l16 = lane & 15;
    const int dsg = lane & 31, jg = lane >> 5;      // us-phase: d-octet / row-parity
    const int qb1 = (quad & 1) << 2;
    const int b = blockIdx.y, nt = blockIdx.x;
    const int j0 = nt << 8;
    const size_t rowbase = (size_t)b * 4096 + j0;

    const u16* qptr = Q + (size_t)b * 16 * 256;
    bf16x8 qfrag[8];
    #pragma unroll
    for (int k0 = 0; k0 < 8; ++k0)
        qfrag[k0] = frag_ld(qptr + l16 * 256 + k0 * 32 + quad * 8);

    float c8[8];
    #pragma unroll
    for (int i = 0; i < 8; ++i) c8[i] = qcg[(size_t)b * 8 + i];

    float4 g4, b4;
    if (FUSE) {
        const int cc = lane << 2;
        g4 = *(const float4*)(gin + cc);
        b4 = *(const float4*)(bin + cc);
    }

    f32x2 acc2[8][4];                // us accumulator [slot][d-pair], packed f32x2
    #pragma unroll
    for (int i = 0; i < 8; ++i)
        #pragma unroll
        for (int k = 0; k < 4; ++k) acc2[i][k] = (f32x2){0.f, 0.f};
    float sacc[4] = {};

    for (int st = 0; st < 4; ++st) {
        const int srow = w * 16;                       // this wave's stash row base
        if (FUSE) {
            // ---- it0: LN 16 rows -> XN global + stash (verified round-6 path) ----
            const int cc = lane << 2;
            #pragma unroll 4
            for (int i = 0; i < 16; ++i) {
                const size_t gr = rowbase + st * 64 + srow + i;
                const float4 x = *(const float4*)(X + gr * 256 + cc);
                float s1 = x.x + x.y + x.z + x.w;
                float s2 = x.x * x.x + x.y * x.y + x.z * x.z + x.w * x.w;
                #pragma unroll
                for (int o = 32; o > 0; o >>= 1) { s1 += __shfl_xor(s1, o); s2 += __shfl_xor(s2, o); }
                const float mu = s1 * (1.f / 256.f);
                const float rs = rsqrtf(s2 * (1.f / 256.f) - mu * mu + 1e-5f);
                ushort4 pk;
                pk.x = f2bf((x.x - mu) * rs * g4.x + b4.x);
                pk.y = f2bf((x.y - mu) * rs * g4.y + b4.y);
                pk.z = f2bf((x.z - mu) * rs * g4.z + b4.z);
                pk.w = f2bf((x.w - mu) * rs * g4.w + b4.w);
                *(ushort4*)(XN + gr * 256 + cc) = pk;
                *(ushort4*)(stash + sw(srow + i, cc)) = pk;
            }
        } else {
            // ---- NEW: stage this wave's 16 rows via global_load_lds (8 x 1KB/wave) ----
            // LDS slot (row, u') holds global 16B-unit u = u' ^ (row&7)  [matches sw()]
            const u16* xb = XN + (rowbase + st * 64) * 256;
            #pragma unroll
            for (int i = 0; i < 8; ++i) {
                const int il = i * 64 + lane;          // 16B-unit index within wave's 8KB
                const int rloc = il >> 5;              // local row 0..15
                const int ug = (il & 31) ^ (rloc & 7); // pre-swizzled global unit
                gld16(xb + (size_t)(srow + rloc) * 256 + ug * 8,
                      stash + ((srow << 5) + il) * 8);
            }
            asm volatile("s_waitcnt vmcnt(0)" ::: "memory");
        }
        // ---- dots: 8 MFMA, B-frags from stash (identical addressing to round 6) ----
        f32x4 dacc = {};
        #pragma unroll
        for (int k0 = 0; k0 < 8; ++k0) {
            const bf16x8 bfr = frag_ld(stash + sw(srow + l16, k0 * 32 + quad * 8));
            dacc = __builtin_amdgcn_mfma_f32_16x16x32_bf16(qfrag[k0], bfr, dacc, 0, 0, 0);
        }
        // ---- softmax over 8 slots for column j = srow + l16 (wave-local) ----
        {
            float v[8];
            #pragma unroll
            for (int r = 0; r < 4; ++r) {
                v[qb1 + r]       = dacc[r];
                v[(qb1 ^ 4) + r] = __shfl_xor(dacc[r], 16);
            }
            #pragma unroll
            for (int i = 0; i < 8; ++i) v[i] += c8[i];
            float m = v[0];
            #pragma unroll
            for (int i = 1; i < 8; ++i) m = fmaxf(m, v[i]);
            float s = 0.f;
            #pragma unroll
            for (int i = 0; i < 8; ++i) { v[i] = __expf(v[i] - m); s += v[i]; }
            const float inv = 1.f / s;
            if (quad < 2) {
                float4 av;
                av.x = v[qb1 + 0] * inv + 1e-8f;
                av.y = v[qb1 + 1] * inv + 1e-8f;
                av.z = v[qb1 + 2] * inv + 1e-8f;
                av.w = v[qb1 + 3] * inv + 1e-8f;
                sacc[0] += av.x; sacc[1] += av.y; sacc[2] += av.z; sacc[3] += av.w;
                *(float4*)&att32[srow + l16][qb1] = av;
                if (write_attn) {
                    const size_t jglob = j0 + st * 64 + srow + l16;
                    attn_out[((size_t)b * 8 + qb1 + 0) * 4096 + jglob] = av.x;
                    attn_out[((size_t)b * 8 + qb1 + 1) * 4096 + jglob] = av.y;
                    attn_out[((size_t)b * 8 + qb1 + 2) * 4096 + jglob] = av.z;
                    attn_out[((size_t)b * 8 + qb1 + 3) * 4096 + jglob] = av.w;
                }
            }
        }
        // ---- us: packed-FMA accumulation from the LDS stash (verified round-6 path) ----
        #pragma unroll
        for (int jj = 0; jj < 8; ++jj) {
            const int row = srow + jj * 2 + jg;
            const uint4 raw = *(const uint4*)(stash + sw(row, dsg * 8));
            const float4 a0 = *(const float4*)&att32[row][0];
            const float4 a1 = *(const float4*)&att32[row][4];
            f32x2 xf[4];
            xf[0] = bf2(raw.x); xf[1] = bf2(raw.y); xf[2] = bf2(raw.z); xf[3] = bf2(raw.w);
            const float av8[8] = {a0.x, a0.y, a0.z, a0.w, a1.x, a1.y, a1.z, a1.w};
            #pragma unroll
            for (int i = 0; i < 8; ++i) {
                const f32x2 aa = (f32x2){av8[i], av8[i]};
                #pragma unroll
                for (int k = 0; k < 4; ++k)
                    acc2[i][k] = aa * xf[k] + acc2[i][k];
            }
        }
    }

    // ---- epilogue: per-wave partial stores (no LDS, no barriers) ----
    #pragma unroll
    for (int i = 0; i < 8; ++i)
        #pragma unroll
        for (int k = 0; k < 4; ++k) {
            acc2[i][k][0] += __shfl_xor(acc2[i][k][0], 32);
            acc2[i][k][1] += __shfl_xor(acc2[i][k][1], 32);
        }
    const int unit = nt * 4 + w;
    if (jg == 0) {
        const size_t pb = ((size_t)unit * 64 + b) * 8;
        #pragma unroll
        for (int i = 0; i < 8; ++i) {
            float4 lo, hi;
            lo.x = acc2[i][0][0]; lo.y = acc2[i][0][1]; lo.z = acc2[i][1][0]; lo.w = acc2[i][1][1];
            hi.x = acc2[i][2][0]; hi.y = acc2[i][2][1]; hi.z = acc2[i][3][0]; hi.w = acc2[i][3][1];
            *(float4*)&part[(pb + i) * 256 + dsg * 8]     = lo;
            *(float4*)&part[(pb + i) * 256 + dsg * 8 + 4] = hi;
        }
    }
    #pragma unroll
    for (int r = 0; r < 4; ++r)
        #pragma unroll
        for (int o = 1; o < 16; o <<= 1) sacc[r] += __shfl_xor(sacc[r], o);
    if (l16 == 0 && quad < 2) {
        #pragma unroll
        for (int r = 0; r < 4; ++r)
            part2[((size_t)unit * 64 + b) * 8 + qb1 + r] = sacc[r];
    }
}

// ---------------- kB3: US-reduce + Wv GEMV + GRU + LN + MLP, all split-K ----------------
// grid 256 blocks (2 rows each), 256 threads = (kp 0..3) x (c 0..63)
__global__ __launch_bounds__(256) void kB3(
    const float* __restrict__ part, const float* __restrict__ part2,
    const float* __restrict__ WvT, const float* __restrict__ bv,
    const float* __restrict__ sl_in,
    const float* __restrict__ WihT, const float* __restrict__ bih,
    const float* __restrict__ WhhT, const float* __restrict__ bhh,
    const float* __restrict__ W1T, const float* __restrict__ b1,
    const float* __restrict__ W2T, const float* __restrict__ b2,
    const float* __restrict__ gf, const float* __restrict__ bff,
    float* __restrict__ sl_out)
{
    __shared__ float Ul[2][256], Sl[2][256];
    __shared__ float red[2][4][6][256];     // 48 KB, reused across phases
    __shared__ float SNl[2][256];
    __shared__ float cw[2][2][4];
    __shared__ float Ssl[2];
    const int t = threadIdx.x;
    const int kp = t >> 6, c = t & 63;
    const int row0 = blockIdx.x * 2;

    #pragma unroll
    for (int r = 0; r < 2; ++r) {
        const int row = row0 + r;
        const int b = row >> 3, s = row & 7;
        float ua0 = 0.f, ua1 = 0.f;
        #pragma unroll 8
        for (int u = 0; u < 64; u += 2) {
            ua0 += part[(((size_t)u * 64 + b) * 8 + s) * 256 + t];
            ua1 += part[(((size_t)(u + 1) * 64 + b) * 8 + s) * 256 + t];
        }
        Ul[r][t] = ua0 + ua1;
        Sl[r][t] = sl_in[(size_t)row * 256 + t];
    }
    if (t < 2) {
        const int row = row0 + t;
        const int b = row >> 3, s = row & 7;
        float ss = 0.f;
        #pragma unroll
        for (int u = 0; u < 64; ++u) ss += part2[((size_t)u * 64 + b) * 8 + s];
        Ssl[t] = ss;
    }
    __syncthreads();

    {
        float va[2][4] = {};
        #pragma unroll 4
        for (int dd = 0; dd < 64; ++dd) {
            const int d = kp * 64 + dd;
            const float* wr = WvT + (size_t)d * 256;
            const float u0 = Ul[0][d], u1 = Ul[1][d];
            #pragma unroll
            for (int cg = 0; cg < 4; ++cg) {
                const float wv = wr[cg * 64 + c];
                va[0][cg] += wv * u0;
                va[1][cg] += wv * u1;
            }
        }
        #pragma unroll
        for (int r = 0; r < 2; ++r)
            #pragma unroll
            for (int cg = 0; cg < 4; ++cg)
                red[r][kp][0][cg * 64 + c] = va[r][cg];
    }
    __syncthreads();
    const float bvt = bv[t];
    float upd2[2];
    #pragma unroll
    for (int r = 0; r < 2; ++r)
        upd2[r] = red[r][0][0][t] + red[r][1][0][t] + red[r][2][0][t] + red[r][3][0][t]
                + Ssl[r] * bvt;
    __syncthreads();
    #pragma unroll
    for (int r = 0; r < 2; ++r) Ul[r][t] = upd2[r];
    __syncthreads();

    float ga[2][4][6] = {};
    #pragma unroll 2
    for (int dd = 0; dd < 64; ++dd) {
        const int d = kp * 64 + dd;
        const float* wi = WihT + (size_t)d * 768;
        const float* wh = WhhT + (size_t)d * 768;
        const float u0 = Ul[0][d], u1 = Ul[1][d];
        const float s0 = Sl[0][d], s1 = Sl[1][d];
        #pragma unroll
        for (int cg = 0; cg < 4; ++cg) {
            const int t2 = cg * 64 + c;
            const float wa = wi[t2], wb = wi[256 + t2], wc = wi[512 + t2];
            const float wd = wh[t2], we = wh[256 + t2], wf = wh[512 + t2];
            ga[0][cg][0] += wa * u0; ga[0][cg][1] += wb * u0; ga[0][cg][2] += wc * u0;
            ga[0][cg][3] += wd * s0; ga[0][cg][4] += we * s0; ga[0][cg][5] += wf * s0;
            ga[1][cg][0] += wa * u1; ga[1][cg][1] += wb * u1; ga[1][cg][2] += wc * u1;
            ga[1][cg][3] += wd * s1; ga[1][cg][4] += we * s1; ga[1][cg][5] += wf * s1;
        }
    }
    #pragma unroll
    for (int r = 0; r < 2; ++r)
        #pragma unroll
        for (int cg = 0; cg < 4; ++cg)
            #pragma unroll
            for (int g = 0; g < 6; ++g)
                red[r][kp][g][cg * 64 + c] = ga[r][cg][g];
    __syncthreads();

    const float b_ir = bih[t], b_iz = bih[256 + t], b_in = bih[512 + t];
    const float b_hr = bhh[t], b_hz = bhh[256 + t], b_hn = bhh[512 + t];
    float hnew[2];
    #pragma unroll
    for (int r = 0; r < 2; ++r) {
        float s6[6];
        #pragma unroll
        for (int g = 0; g < 6; ++g)
            s6[g] = red[r][0][g][t] + red[r][1][g][t] + red[r][2][g][t] + red[r][3][g][t];
        const float rg = sigm(s6[0] + b_ir + s6[3] + b_hr);
        const float zg = sigm(s6[1] + b_iz + s6[4] + b_hz);
        const float ng = tanhf(s6[2] + b_in + rg * (s6[5] + b_hn));
        hnew[r] = (1.f - zg) * ng + zg * Sl[r][t];
    }
    #pragma unroll
    for (int r = 0; r < 2; ++r) {
        float s1 = hnew[r], s2 = hnew[r] * hnew[r];
        #pragma unroll
        for (int o = 32; o > 0; o >>= 1) { s1 += __shfl_xor(s1, o); s2 += __shfl_xor(s2, o); }
        if (c == 0) { cw[r][0][kp] = s1; cw[r][1][kp] = s2; }
    }
    __syncthreads();
    const float gft = gf[t], bfft = bff[t];
    #pragma unroll
    for (int r = 0; r < 2; ++r) {
        const float s1 = cw[r][0][0] + cw[r][0][1] + cw[r][0][2] + cw[r][0][3];
        const float s2 = cw[r][1][0] + cw[r][1][1] + cw[r][1][2] + cw[r][1][3];
        const float mu = s1 * (1.f / 256.f);
        const float rs = rsqrtf(s2 * (1.f / 256.f) - mu * mu + 1e-5f);
        SNl[r][t] = (hnew[r] - mu) * rs * gft + bfft;
    }
    __syncthreads();

    {
        float m1[2][4] = {};
        #pragma unroll 4
        for (int dd = 0; dd < 64; ++dd) {
            const int d = kp * 64 + dd;
            const float* wr = W1T + (size_t)d * 256;
            const float n0 = SNl[0][d], n1 = SNl[1][d];
            #pragma unroll
            for (int cg = 0; cg < 4; ++cg) {
                const float wv = wr[cg * 64 + c];
                m1[0][cg] += wv * n0;
                m1[1][cg] += wv * n1;
            }
        }
        #pragma unroll
        for (int r = 0; r < 2; ++r)
            #pragma unroll
            for (int cg = 0; cg < 4; ++cg)
                red[r][kp][0][cg * 64 + c] = m1[r][cg];
    }
    __syncthreads();
    const float b1t = b1[t];
    float h1v[2];
    #pragma unroll
    for (int r = 0; r < 2; ++r)
        h1v[r] = fmaxf(red[r][0][0][t] + red[r][1][0][t] + red[r][2][0][t] + red[r][3][0][t]
                       + b1t, 0.f);
    __syncthreads();
    #pragma unroll
    for (int r = 0; r < 2; ++r) SNl[r][t] = h1v[r];
    __syncthreads();
    {
        float m2[2][4] = {};
        #pragma unroll 4
        for (int dd = 0; dd < 64; ++dd) {
            const int d = kp * 64 + dd;
            const float* wr = W2T + (size_t)d * 256;
            const float x0 = SNl[0][d], x1 = SNl[1][d];
            #pragma unroll
            for (int cg = 0; cg < 4; ++cg) {
                const float wv = wr[cg * 64 + c];
                m2[0][cg] += wv * x0;
                m2[1][cg] += wv * x1;
            }
        }
        #pragma unroll
        for (int r = 0; r < 2; ++r)
            #pragma unroll
            for (int cg = 0; cg < 4; ++cg)
                red[r][kp][1][cg * 64 + c] = m2[r][cg];
    }
    __syncthreads();
    const float b2t = b2[t];
    #pragma unroll
    for (int r = 0; r < 2; ++r) {
        const float o = red[r][0][1][t] + red[r][1][1][t] + red[r][2][1][t] + red[r][3][1][t];
        sl_out[(size_t)(row0 + r) * 256 + t] = hnew[r] + o + b2t;
    }
}

// ---------------- launch ----------------
extern "C" void kernel_launch(void* const* d_in, const int* in_sizes, int n_in,
                              void* d_out, int out_size, void* d_ws, size_t ws_size,
                              hipStream_t stream) {
    const float* inputs = (const float*)d_in[0];
    const float* noise  = (const float*)d_in[1];
    const float* smean  = (const float*)d_in[2];
    const float* slogv  = (const float*)d_in[3];
    const float* Wq  = (const float*)d_in[4];
    const float* bq  = (const float*)d_in[5];
    const float* Wk  = (const float*)d_in[6];
    const float* bk  = (const float*)d_in[7];
    const float* Wv  = (const float*)d_in[8];
    const float* bv  = (const float*)d_in[9];
    const float* Wih = (const float*)d_in[10];
    const float* bih = (const float*)d_in[11];
    const float* Whh = (const float*)d_in[12];
    const float* bhh = (const float*)d_in[13];
    const float* W1  = (const float*)d_in[14];
    const float* b1  = (const float*)d_in[15];
    const float* W2  = (const float*)d_in[16];
    const float* b2  = (const float*)d_in[17];
    const float* gin = (const float*)d_in[18];
    const float* bin = (const float*)d_in[19];
    const float* gs  = (const float*)d_in[20];
    const float* bs  = (const float*)d_in[21];
    const float* gf  = (const float*)d_in[22];
    const float* bff = (const float*)d_in[23];

    // workspace layout (~171.6 MB)
    char* ws = (char*)d_ws;
    u16*  XNw    = (u16*)(ws);                          // 134,217,728  LN(x) bf16 [B,N,D]
    u16*  qw     = (u16*)(ws + 134217728ull);           //     524,288
    float* slots = (float*)(ws + 134742016ull);         //     524,288
    float* Wqkw  = (float*)(ws + 135266304ull);         //     262,144
    float* wbc   = (float*)(ws + 135528448ull);         //       4,096
    float* qcw   = (float*)(ws + 135532544ull);         //       4,096
    float* WvT   = (float*)(ws + 135536640ull);         //     262,144
    float* WihT  = (float*)(ws + 135798784ull);         //     786,432
    float* WhhT  = (float*)(ws + 136585216ull);         //     786,432
    float* W1T   = (float*)(ws + 137371648ull);         //     262,144
    float* W2T   = (float*)(ws + 137633792ull);         //     262,144
    float* partw = (float*)(ws + 137895936ull);         //  33,554,432  [64][64][8][256]
    float* part2w= (float*)(ws + 171450368ull);         //     131,072  [64][64][8]

    float* out = (float*)d_out;
    float* attn_out = out + 131072;                     // [B,S,N] after slots [B,S,D]

    kSetup<<<1346, 256, 0, stream>>>(noise, smean, slogv, slots,
                                     Wq, Wk, bq, bk, Wqkw, wbc,
                                     Wv, WvT, Wih, WihT, Whh, WhhT, W1, W1T, W2, W2T);
    for (int it = 0; it < 3; ++it) {
        kSn<<<dim3(4, 64), 256, 0, stream>>>(slots, gs, bs, Wqkw, wbc, qw, qcw);
        if (it == 0)
            kF<1><<<dim3(16, 64), 256, 0, stream>>>(inputs, gin, bin, qw, qcw, XNw,
                                                    attn_out, partw, part2w, 0);
        else
            kF<0><<<dim3(16, 64), 256, 0, stream>>>(inputs, gin, bin, qw, qcw, XNw,
                                                    attn_out, partw, part2w, it == 2);
        kB3<<<256, 256, 0, stream>>>(partw, part2w, WvT, bv, slots,
                                     WihT, bih, WhhT, bhh, W1T, b1, W2T, b2, gf, bff,
                                     (it == 2) ? out : slots);
    }
}

// Round 10
// 706.263 us; speedup vs baseline: 1.3185x; 1.3185x over previous
//
#include <hip/hip_runtime.h>

typedef unsigned short u16;
typedef __bf16 bf16x8 __attribute__((ext_vector_type(8)));
typedef float f32x4 __attribute__((ext_vector_type(4)));
typedef float f32x2 __attribute__((ext_vector_type(2)));

#define DEV static __device__ __forceinline__

DEV u16 f2bf(float f) {
    unsigned int u = __builtin_bit_cast(unsigned int, f);
    u += 0x7FFFu + ((u >> 16) & 1u);
    return (u16)(u >> 16);
}

DEV bf16x8 frag_ld(const u16* p) {  // p must be 16B aligned
    return __builtin_bit_cast(bf16x8, *(const uint4*)p);
}

DEV float sigm(float x) { return 1.f / (1.f + __expf(-x)); }

DEV float blo(unsigned u) { return __builtin_bit_cast(float, u << 16); }
DEV float bhi(unsigned u) { return __builtin_bit_cast(float, u & 0xffff0000u); }
DEV f32x2 bf2(unsigned u) { return (f32x2){ blo(u), bhi(u) }; }

// stash-half [64][256] u16, 16B-unit XOR swizzle by row&7 (u16-index units: <<3)
DEV int sw(int row, int colu16) { return row * 256 + (colu16 ^ ((row & 7) << 3)); }

// global -> LDS direct (width 16B); lds dest must be wave-uniform base + lane*16
DEV void gld16(const u16* g, u16* l) {
    __builtin_amdgcn_global_load_lds(
        (const __attribute__((address_space(1))) unsigned int*)g,
        (__attribute__((address_space(3))) unsigned int*)l, 16, 0, 0);
}

// ---------------- kSetupLN: one-time prep + LN(inputs) in ONE dispatch ----------------
// blocks [0,2048): LN 128 rows each | [2048,2560): slot init | [2560,2818): Wqk fold
// | [2818,3394): 5 weight transposes
__global__ __launch_bounds__(256) void kSetupLN(
    const float* __restrict__ X, const float* __restrict__ gin, const float* __restrict__ bin,
    u16* __restrict__ XN,
    const float* __restrict__ noise, const float* __restrict__ mean,
    const float* __restrict__ logv, float* __restrict__ slots,
    const float* __restrict__ Wq, const float* __restrict__ Wk,
    const float* __restrict__ bq, const float* __restrict__ bk,
    float* __restrict__ Wqk, float* __restrict__ wbc,
    const float* __restrict__ Wv,  float* __restrict__ WvT,
    const float* __restrict__ Wih, float* __restrict__ WihT,
    const float* __restrict__ Whh, float* __restrict__ WhhT,
    const float* __restrict__ W1,  float* __restrict__ W1T,
    const float* __restrict__ W2,  float* __restrict__ W2T)
{
    __shared__ float tile[32][33];
    const int bid = blockIdx.x, t = threadIdx.x;
    if (bid < 2048) {                      // LN(inputs) -> XN bf16 (verbatim kLN body)
        const int w = t >> 6, lane = t & 63;
        const int c = lane << 2;
        const float4 g4 = *(const float4*)(gin + c);
        const float4 b4 = *(const float4*)(bin + c);
        const size_t r0 = (size_t)bid * 128 + (size_t)w * 32;
        #pragma unroll 4
        for (int i = 0; i < 32; ++i) {
            const float4 x = *(const float4*)(X + (r0 + i) * 256 + c);
            float s1 = x.x + x.y + x.z + x.w;
            float s2 = x.x * x.x + x.y * x.y + x.z * x.z + x.w * x.w;
            #pragma unroll
            for (int o = 32; o > 0; o >>= 1) { s1 += __shfl_xor(s1, o); s2 += __shfl_xor(s2, o); }
            const float mu = s1 * (1.f / 256.f);
            const float rs = rsqrtf(s2 * (1.f / 256.f) - mu * mu + 1e-5f);
            ushort4 pk;
            pk.x = f2bf((x.x - mu) * rs * g4.x + b4.x);
            pk.y = f2bf((x.y - mu) * rs * g4.y + b4.y);
            pk.z = f2bf((x.z - mu) * rs * g4.z + b4.z);
            pk.w = f2bf((x.w - mu) * rs * g4.w + b4.w);
            *(ushort4*)(XN + (r0 + i) * 256 + c) = pk;
        }
        return;
    }
    if (bid < 2560) {                      // slots = mean + exp(logvar)*noise
        const int id = (bid - 2048) * 256 + t;
        const int d = id & 255;
        slots[id] = mean[d] + __expf(logv[d]) * noise[id];
        return;
    }
    if (bid < 2818) {                      // Wqk fold + wbc extras
        const int a = bid - 2560, e = t;
        if (a < 256) {
            float acc = 0.f;
            for (int d = 0; d < 256; ++d) acc += Wq[(size_t)d * 256 + a] * Wk[(size_t)d * 256 + e];
            Wqk[(size_t)a * 256 + e] = acc;
        } else if (a == 256) {
            float acc = 0.f;
            for (int d = 0; d < 256; ++d) acc += bq[d] * Wk[(size_t)d * 256 + e];
            wbc[e] = acc;
        } else {
            float acc = 0.f;
            for (int d = 0; d < 256; ++d) acc += Wq[(size_t)d * 256 + e] * bk[d];
            wbc[256 + e] = acc;
            if (e == 0) {
                float c0 = 0.f;
                for (int d = 0; d < 256; ++d) c0 += bq[d] * bk[d];
                wbc[512] = c0;
            }
        }
        return;
    }
    const int rb = bid - 2818;
    const float* in; float* outp; int R, k;
    if (rb < 64)       { in = Wv;  outp = WvT;  R = 256; k = rb; }
    else if (rb < 256) { in = Wih; outp = WihT; R = 768; k = rb - 64; }
    else if (rb < 448) { in = Whh; outp = WhhT; R = 768; k = rb - 256; }
    else if (rb < 512) { in = W1;  outp = W1T;  R = 256; k = rb - 448; }
    else               { in = W2;  outp = W2T;  R = 256; k = rb - 512; }
    const int bx = k & 7, by = k >> 3;
    const int tx = t & 31, ty = t >> 5;
    const int c0 = bx * 32, r0 = by * 32;
    #pragma unroll
    for (int i = 0; i < 4; ++i)
        tile[ty + i * 8][tx] = in[(size_t)(r0 + ty + i * 8) * 256 + c0 + tx];
    __syncthreads();
    #pragma unroll
    for (int i = 0; i < 4; ++i)
        outp[(size_t)(c0 + ty + i * 8) * R + r0 + tx] = tile[tx][ty + i * 8];
}

// ---------------- kSn: LN(slots) -> qk = SCALE*(sn@Wqk + bqk) bf16; qc ----------------
__global__ __launch_bounds__(256) void kSn(
    const float* __restrict__ slots, const float* __restrict__ gs, const float* __restrict__ bs,
    const float* __restrict__ Wqk, const float* __restrict__ wbc,
    u16* __restrict__ qo, float* __restrict__ qc)
{
    __shared__ float SN[8][256];
    __shared__ float red2[4][8][64];
    const int t = threadIdx.x;
    const int b = blockIdx.y, seg = blockIdx.x;
    const int w = t >> 6, lane = t & 63;
    #pragma unroll
    for (int rr = 0; rr < 2; ++rr) {
        const int r = w * 2 + rr;
        const int c = lane * 4;
        const float4 x = *(const float4*)(slots + ((size_t)b * 8 + r) * 256 + c);
        float s1 = x.x + x.y + x.z + x.w;
        float s2 = x.x * x.x + x.y * x.y + x.z * x.z + x.w * x.w;
        #pragma unroll
        for (int o = 32; o > 0; o >>= 1) { s1 += __shfl_xor(s1, o); s2 += __shfl_xor(s2, o); }
        const float mu = s1 * (1.f / 256.f);
        const float rs = rsqrtf(s2 * (1.f / 256.f) - mu * mu + 1e-5f);
        const float4 g4 = *(const float4*)(gs + c);
        const float4 b4 = *(const float4*)(bs + c);
        SN[r][c + 0] = (x.x - mu) * rs * g4.x + b4.x;
        SN[r][c + 1] = (x.y - mu) * rs * g4.y + b4.y;
        SN[r][c + 2] = (x.z - mu) * rs * g4.z + b4.z;
        SN[r][c + 3] = (x.w - mu) * rs * g4.w + b4.w;
    }
    __syncthreads();
    const int c = seg * 64 + (t & 63);
    const int p = t >> 6;
    float acc[8] = {};
    #pragma unroll 4
    for (int d = p * 64; d < p * 64 + 64; ++d) {
        const float wq = Wqk[(size_t)d * 256 + c];
        #pragma unroll
        for (int r = 0; r < 8; ++r) acc[r] += wq * SN[r][d];
    }
    #pragma unroll
    for (int r = 0; r < 8; ++r) red2[p][r][t & 63] = acc[r];
    __syncthreads();
    const float bb = wbc[c];
    #pragma unroll
    for (int rr = t >> 6; rr < 8; rr += 4) {
        const float s = red2[0][rr][t & 63] + red2[1][rr][t & 63]
                      + red2[2][rr][t & 63] + red2[3][rr][t & 63];
        qo[((size_t)b * 16 + rr) * 256 + c] = f2bf((s + bb) * 0.0625f);
    }
    if (seg == 0) {
        const int r = t >> 5, l = t & 31;
        float a = 0.f;
        #pragma unroll
        for (int d8 = 0; d8 < 8; ++d8) a += SN[r][l * 8 + d8] * wbc[256 + l * 8 + d8];
        #pragma unroll
        for (int o = 16; o > 0; o >>= 1) a += __shfl_xor(a, o);
        if (l == 0) qc[(size_t)b * 8 + r] = 0.0625f * (a + wbc[512]);
    }
}

// ---------------- kF: dots -> softmax -> us, double-buffered staging ----------------
// grid (16 nt of 256 j, 64 b), 256 thr (4 waves). Verified r9 per-wave structure;
// ONLY change: stash is 2 halves; chunk c+1's 8 global_load_lds issue BEFORE computing
// chunk c; counted s_waitcnt vmcnt(8) (never 0 in-loop). Wave-private -> no barriers.
__global__ __launch_bounds__(256, 3) void kF(
    const u16* __restrict__ Q,        // qk_s [B,16,256] bf16 (rows 8..15 unused)
    const float* __restrict__ qcg,    // [B,8]
    const u16* __restrict__ XN,       // [B,4096,256] bf16
    float* __restrict__ attn_out,
    float* __restrict__ part,         // [64][64][8][256] f32 (per-wave partials)
    float* __restrict__ part2,        // [64][64][8]      f32 (attn row-sums)
    int write_attn)
{
    __shared__ __align__(16) u16 stash[2 * 64 * 256];   // 64 KB, 2 halves, XOR-swizzled
    __shared__ __align__(16) float att32[64][8];        // attn f32 [row][slot], wave-private
    const int tid = threadIdx.x;
    const int w = tid >> 6, lane = tid & 63;
    const int quad = lane >> 4, l16 = lane & 15;
    const int dsg = lane & 31, jg = lane >> 5;
    const int qb1 = (quad & 1) << 2;
    const int b = blockIdx.y, nt = blockIdx.x;
    const int j0 = nt << 8;
    const size_t rowbase = (size_t)b * 4096 + j0;
    const int srow = w * 16;                            // this wave's row base in a half

    const u16* qptr = Q + (size_t)b * 16 * 256;
    bf16x8 qfrag[8];
    #pragma unroll
    for (int k0 = 0; k0 < 8; ++k0)
        qfrag[k0] = frag_ld(qptr + l16 * 256 + k0 * 32 + quad * 8);

    float c8[8];
    #pragma unroll
    for (int i = 0; i < 8; ++i) c8[i] = qcg[(size_t)b * 8 + i];

    f32x2 acc2[8][4];
    #pragma unroll
    for (int i = 0; i < 8; ++i)
        #pragma unroll
        for (int k = 0; k < 4; ++k) acc2[i][k] = (f32x2){0.f, 0.f};
    float sacc[4] = {};

    // stage chunk ck's rows (this wave's 16) into stash half h (verbatim r9 mapping)
#define STAGE(ck, h)                                                          \
    {                                                                         \
        const u16* xb = XN + (rowbase + (ck) * 64) * 256;                     \
        u16* dst = stash + (h) * 16384;                                       \
        _Pragma("unroll")                                                     \
        for (int i = 0; i < 8; ++i) {                                         \
            const int il = i * 64 + lane;                                     \
            const int rloc = il >> 5;                                         \
            const int ug = (il & 31) ^ (rloc & 7);                            \
            gld16(xb + (size_t)(srow + rloc) * 256 + ug * 8,                  \
                  dst + ((srow << 5) + il) * 8);                              \
        }                                                                     \
    }

    STAGE(0, 0);
    for (int st = 0; st < 4; ++st) {
        if (st < 3) {
            STAGE(st + 1, (st + 1) & 1);
            asm volatile("s_waitcnt vmcnt(8)" ::: "memory");   // chunk st's loads done
        } else {
            asm volatile("s_waitcnt vmcnt(0)" ::: "memory");   // final drain
        }
        const u16* sh = stash + (st & 1) * 16384;

        // ---- dots: 8 MFMA, B-frags from stash (verbatim r9) ----
        f32x4 dacc = {};
        #pragma unroll
        for (int k0 = 0; k0 < 8; ++k0) {
            const bf16x8 bfr = frag_ld(sh + sw(srow + l16, k0 * 32 + quad * 8));
            dacc = __builtin_amdgcn_mfma_f32_16x16x32_bf16(qfrag[k0], bfr, dacc, 0, 0, 0);
        }
        // ---- softmax over 8 slots for column j = srow + l16 (wave-local) ----
        {
            float v[8];
            #pragma unroll
            for (int r = 0; r < 4; ++r) {
                v[qb1 + r]       = dacc[r];
                v[(qb1 ^ 4) + r] = __shfl_xor(dacc[r], 16);
            }
            #pragma unroll
            for (int i = 0; i < 8; ++i) v[i] += c8[i];
            float m = v[0];
            #pragma unroll
            for (int i = 1; i < 8; ++i) m = fmaxf(m, v[i]);
            float s = 0.f;
            #pragma unroll
            for (int i = 0; i < 8; ++i) { v[i] = __expf(v[i] - m); s += v[i]; }
            const float inv = 1.f / s;
            if (quad < 2) {
                float4 av;
                av.x = v[qb1 + 0] * inv + 1e-8f;
                av.y = v[qb1 + 1] * inv + 1e-8f;
                av.z = v[qb1 + 2] * inv + 1e-8f;
                av.w = v[qb1 + 3] * inv + 1e-8f;
                sacc[0] += av.x; sacc[1] += av.y; sacc[2] += av.z; sacc[3] += av.w;
                *(float4*)&att32[srow + l16][qb1] = av;
                if (write_attn) {
                    const size_t jglob = j0 + st * 64 + srow + l16;
                    attn_out[((size_t)b * 8 + qb1 + 0) * 4096 + jglob] = av.x;
                    attn_out[((size_t)b * 8 + qb1 + 1) * 4096 + jglob] = av.y;
                    attn_out[((size_t)b * 8 + qb1 + 2) * 4096 + jglob] = av.z;
                    attn_out[((size_t)b * 8 + qb1 + 3) * 4096 + jglob] = av.w;
                }
            }
        }
        // ---- us: packed-FMA from the stash (verbatim r9) ----
        #pragma unroll
        for (int jj = 0; jj < 8; ++jj) {
            const int row = srow + jj * 2 + jg;
            const uint4 raw = *(const uint4*)(sh + sw(row, dsg * 8));
            const float4 a0 = *(const float4*)&att32[row][0];
            const float4 a1 = *(const float4*)&att32[row][4];
            f32x2 xf[4];
            xf[0] = bf2(raw.x); xf[1] = bf2(raw.y); xf[2] = bf2(raw.z); xf[3] = bf2(raw.w);
            const float av8[8] = {a0.x, a0.y, a0.z, a0.w, a1.x, a1.y, a1.z, a1.w};
            #pragma unroll
            for (int i = 0; i < 8; ++i) {
                const f32x2 aa = (f32x2){av8[i], av8[i]};
                #pragma unroll
                for (int k = 0; k < 4; ++k)
                    acc2[i][k] = aa * xf[k] + acc2[i][k];
            }
        }
    }
#undef STAGE

    // ---- epilogue: per-wave partial stores (verbatim r9) ----
    #pragma unroll
    for (int i = 0; i < 8; ++i)
        #pragma unroll
        for (int k = 0; k < 4; ++k) {
            acc2[i][k][0] += __shfl_xor(acc2[i][k][0], 32);
            acc2[i][k][1] += __shfl_xor(acc2[i][k][1], 32);
        }
    const int unit = nt * 4 + w;
    if (jg == 0) {
        const size_t pb = ((size_t)unit * 64 + b) * 8;
        #pragma unroll
        for (int i = 0; i < 8; ++i) {
            float4 lo, hi;
            lo.x = acc2[i][0][0]; lo.y = acc2[i][0][1]; lo.z = acc2[i][1][0]; lo.w = acc2[i][1][1];
            hi.x = acc2[i][2][0]; hi.y = acc2[i][2][1]; hi.z = acc2[i][3][0]; hi.w = acc2[i][3][1];
            *(float4*)&part[(pb + i) * 256 + dsg * 8]     = lo;
            *(float4*)&part[(pb + i) * 256 + dsg * 8 + 4] = hi;
        }
    }
    #pragma unroll
    for (int r = 0; r < 4; ++r)
        #pragma unroll
        for (int o = 1; o < 16; o <<= 1) sacc[r] += __shfl_xor(sacc[r], o);
    if (l16 == 0 && quad < 2) {
        #pragma unroll
        for (int r = 0; r < 4; ++r)
            part2[((size_t)unit * 64 + b) * 8 + qb1 + r] = sacc[r];
    }
}

// ---------------- kB3: US-reduce + Wv GEMV + GRU + LN + MLP, all split-K ----------------
// grid 256 blocks (2 rows each), 256 threads = (kp 0..3) x (c 0..63)
__global__ __launch_bounds__(256) void kB3(
    const float* __restrict__ part, const float* __restrict__ part2,
    const float* __restrict__ WvT, const float* __restrict__ bv,
    const float* __restrict__ sl_in,
    const float* __restrict__ WihT, const float* __restrict__ bih,
    const float* __restrict__ WhhT, const float* __restrict__ bhh,
    const float* __restrict__ W1T, const float* __restrict__ b1,
    const float* __restrict__ W2T, const float* __restrict__ b2,
    const float* __restrict__ gf, const float* __restrict__ bff,
    float* __restrict__ sl_out)
{
    __shared__ float Ul[2][256], Sl[2][256];
    __shared__ float red[2][4][6][256];
    __shared__ float SNl[2][256];
    __shared__ float cw[2][2][4];
    __shared__ float Ssl[2];
    const int t = threadIdx.x;
    const int kp = t >> 6, c = t & 63;
    const int row0 = blockIdx.x * 2;

    #pragma unroll
    for (int r = 0; r < 2; ++r) {
        const int row = row0 + r;
        const int b = row >> 3, s = row & 7;
        float ua0 = 0.f, ua1 = 0.f;
        #pragma unroll 8
        for (int u = 0; u < 64; u += 2) {
            ua0 += part[(((size_t)u * 64 + b) * 8 + s) * 256 + t];
            ua1 += part[(((size_t)(u + 1) * 64 + b) * 8 + s) * 256 + t];
        }
        Ul[r][t] = ua0 + ua1;
        Sl[r][t] = sl_in[(size_t)row * 256 + t];
    }
    if (t < 2) {
        const int row = row0 + t;
        const int b = row >> 3, s = row & 7;
        float ss = 0.f;
        #pragma unroll
        for (int u = 0; u < 64; ++u) ss += part2[((size_t)u * 64 + b) * 8 + s];
        Ssl[t] = ss;
    }
    __syncthreads();

    {
        float va[2][4] = {};
        #pragma unroll 4
        for (int dd = 0; dd < 64; ++dd) {
            const int d = kp * 64 + dd;
            const float* wr = WvT + (size_t)d * 256;
            const float u0 = Ul[0][d], u1 = Ul[1][d];
            #pragma unroll
            for (int cg = 0; cg < 4; ++cg) {
                const float wv = wr[cg * 64 + c];
                va[0][cg] += wv * u0;
                va[1][cg] += wv * u1;
            }
        }
        #pragma unroll
        for (int r = 0; r < 2; ++r)
            #pragma unroll
            for (int cg = 0; cg < 4; ++cg)
                red[r][kp][0][cg * 64 + c] = va[r][cg];
    }
    __syncthreads();
    const float bvt = bv[t];
    float upd2[2];
    #pragma unroll
    for (int r = 0; r < 2; ++r)
        upd2[r] = red[r][0][0][t] + red[r][1][0][t] + red[r][2][0][t] + red[r][3][0][t]
                + Ssl[r] * bvt;
    __syncthreads();
    #pragma unroll
    for (int r = 0; r < 2; ++r) Ul[r][t] = upd2[r];
    __syncthreads();

    float ga[2][4][6] = {};
    #pragma unroll 2
    for (int dd = 0; dd < 64; ++dd) {
        const int d = kp * 64 + dd;
        const float* wi = WihT + (size_t)d * 768;
        const float* wh = WhhT + (size_t)d * 768;
        const float u0 = Ul[0][d], u1 = Ul[1][d];
        const float s0 = Sl[0][d], s1 = Sl[1][d];
        #pragma unroll
        for (int cg = 0; cg < 4; ++cg) {
            const int t2 = cg * 64 + c;
            const float wa = wi[t2], wb = wi[256 + t2], wc = wi[512 + t2];
            const float wd = wh[t2], we = wh[256 + t2], wf = wh[512 + t2];
            ga[0][cg][0] += wa * u0; ga[0][cg][1] += wb * u0; ga[0][cg][2] += wc * u0;
            ga[0][cg][3] += wd * s0; ga[0][cg][4] += we * s0; ga[0][cg][5] += wf * s0;
            ga[1][cg][0] += wa * u1; ga[1][cg][1] += wb * u1; ga[1][cg][2] += wc * u1;
            ga[1][cg][3] += wd * s1; ga[1][cg][4] += we * s1; ga[1][cg][5] += wf * s1;
        }
    }
    #pragma unroll
    for (int r = 0; r < 2; ++r)
        #pragma unroll
        for (int cg = 0; cg < 4; ++cg)
            #pragma unroll
            for (int g = 0; g < 6; ++g)
                red[r][kp][g][cg * 64 + c] = ga[r][cg][g];
    __syncthreads();

    const float b_ir = bih[t], b_iz = bih[256 + t], b_in = bih[512 + t];
    const float b_hr = bhh[t], b_hz = bhh[256 + t], b_hn = bhh[512 + t];
    float hnew[2];
    #pragma unroll
    for (int r = 0; r < 2; ++r) {
        float s6[6];
        #pragma unroll
        for (int g = 0; g < 6; ++g)
            s6[g] = red[r][0][g][t] + red[r][1][g][t] + red[r][2][g][t] + red[r][3][g][t];
        const float rg = sigm(s6[0] + b_ir + s6[3] + b_hr);
        const float zg = sigm(s6[1] + b_iz + s6[4] + b_hz);
        const float ng = tanhf(s6[2] + b_in + rg * (s6[5] + b_hn));
        hnew[r] = (1.f - zg) * ng + zg * Sl[r][t];
    }
    #pragma unroll
    for (int r = 0; r < 2; ++r) {
        float s1 = hnew[r], s2 = hnew[r] * hnew[r];
        #pragma unroll
        for (int o = 32; o > 0; o >>= 1) { s1 += __shfl_xor(s1, o); s2 += __shfl_xor(s2, o); }
        if (c == 0) { cw[r][0][kp] = s1; cw[r][1][kp] = s2; }
    }
    __syncthreads();
    const float gft = gf[t], bfft = bff[t];
    #pragma unroll
    for (int r = 0; r < 2; ++r) {
        const float s1 = cw[r][0][0] + cw[r][0][1] + cw[r][0][2] + cw[r][0][3];
        const float s2 = cw[r][1][0] + cw[r][1][1] + cw[r][1][2] + cw[r][1][3];
        const float mu = s1 * (1.f / 256.f);
        const float rs = rsqrtf(s2 * (1.f / 256.f) - mu * mu + 1e-5f);
        SNl[r][t] = (hnew[r] - mu) * rs * gft + bfft;
    }
    __syncthreads();

    {
        float m1[2][4] = {};
        #pragma unroll 4
        for (int dd = 0; dd < 64; ++dd) {
            const int d = kp * 64 + dd;
            const float* wr = W1T + (size_t)d * 256;
            const float n0 = SNl[0][d], n1 = SNl[1][d];
            #pragma unroll
            for (int cg = 0; cg < 4; ++cg) {
                const float wv = wr[cg * 64 + c];
                m1[0][cg] += wv * n0;
                m1[1][cg] += wv * n1;
            }
        }
        #pragma unroll
        for (int r = 0; r < 2; ++r)
            #pragma unroll
            for (int cg = 0; cg < 4; ++cg)
                red[r][kp][0][cg * 64 + c] = m1[r][cg];
    }
    __syncthreads();
    const float b1t = b1[t];
    float h1v[2];
    #pragma unroll
    for (int r = 0; r < 2; ++r)
        h1v[r] = fmaxf(red[r][0][0][t] + red[r][1][0][t] + red[r][2][0][t] + red[r][3][0][t]
                       + b1t, 0.f);
    __syncthreads();
    #pragma unroll
    for (int r = 0; r < 2; ++r) SNl[r][t] = h1v[r];
    __syncthreads();
    {
        float m2[2][4] = {};
        #pragma unroll 4
        for (int dd = 0; dd < 64; ++dd) {
            const int d = kp * 64 + dd;
            const float* wr = W2T + (size_t)d * 256;
            const float x0 = SNl[0][d], x1 = SNl[1][d];
            #pragma unroll
            for (int cg = 0; cg < 4; ++cg) {
                const float wv = wr[cg * 64 + c];
                m2[0][cg] += wv * x0;
                m2[1][cg] += wv * x1;
            }
        }
        #pragma unroll
        for (int r = 0; r < 2; ++r)
            #pragma unroll
            for (int cg = 0; cg < 4; ++cg)
                red[r][kp][1][cg * 64 + c] = m2[r][cg];
    }
    __syncthreads();
    const float b2t = b2[t];
    #pragma unroll
    for (int r = 0; r < 2; ++r) {
        const float o = red[r][0][1][t] + red[r][1][1][t] + red[r][2][1][t] + red[r][3][1][t];
        sl_out[(size_t)(row0 + r) * 256 + t] = hnew[r] + o + b2t;
    }
}

// ---------------- launch ----------------
extern "C" void kernel_launch(void* const* d_in, const int* in_sizes, int n_in,
                              void* d_out, int out_size, void* d_ws, size_t ws_size,
                              hipStream_t stream) {
    const float* inputs = (const float*)d_in[0];
    const float* noise  = (const float*)d_in[1];
    const float* smean  = (const float*)d_in[2];
    const float* slogv  = (const float*)d_in[3];
    const float* Wq  = (const float*)d_in[4];
    const float* bq  = (const float*)d_in[5];
    const float* Wk  = (const float*)d_in[6];
    const float* bk  = (const float*)d_in[7];
    const float* Wv  = (const float*)d_in[8];
    const float* bv  = (const float*)d_in[9];
    const float* Wih = (const float*)d_in[10];
    const float* bih = (const float*)d_in[11];
    const float* Whh = (const float*)d_in[12];
    const float* bhh = (const float*)d_in[13];
    const float* W1  = (const float*)d_in[14];
    const float* b1  = (const float*)d_in[15];
    const float* W2  = (const float*)d_in[16];
    const float* b2  = (const float*)d_in[17];
    const float* gin = (const float*)d_in[18];
    const float* bin = (const float*)d_in[19];
    const float* gs  = (const float*)d_in[20];
    const float* bs  = (const float*)d_in[21];
    const float* gf  = (const float*)d_in[22];
    const float* bff = (const float*)d_in[23];

    // workspace layout (~171.6 MB)
    char* ws = (char*)d_ws;
    u16*  XNw    = (u16*)(ws);                          // 134,217,728  LN(x) bf16 [B,N,D]
    u16*  qw     = (u16*)(ws + 134217728ull);           //     524,288
    float* slots = (float*)(ws + 134742016ull);         //     524,288
    float* Wqkw  = (float*)(ws + 135266304ull);         //     262,144
    float* wbc   = (float*)(ws + 135528448ull);         //       4,096
    float* qcw   = (float*)(ws + 135532544ull);         //       4,096
    float* WvT   = (float*)(ws + 135536640ull);         //     262,144
    float* WihT  = (float*)(ws + 135798784ull);         //     786,432
    float* WhhT  = (float*)(ws + 136585216ull);         //     786,432
    float* W1T   = (float*)(ws + 137371648ull);         //     262,144
    float* W2T   = (float*)(ws + 137633792ull);         //     262,144
    float* partw = (float*)(ws + 137895936ull);         //  33,554,432  [64][64][8][256]
    float* part2w= (float*)(ws + 171450368ull);         //     131,072  [64][64][8]

    float* out = (float*)d_out;
    float* attn_out = out + 131072;                     // [B,S,N] after slots [B,S,D]

    kSetupLN<<<3394, 256, 0, stream>>>(inputs, gin, bin, XNw,
                                       noise, smean, slogv, slots,
                                       Wq, Wk, bq, bk, Wqkw, wbc,
                                       Wv, WvT, Wih, WihT, Whh, WhhT, W1, W1T, W2, W2T);
    for (int it = 0; it < 3; ++it) {
        kSn<<<dim3(4, 64), 256, 0, stream>>>(slots, gs, bs, Wqkw, wbc, qw, qcw);
        kF<<<dim3(16, 64), 256, 0, stream>>>(qw, qcw, XNw, attn_out, partw, part2w, it == 2);
        kB3<<<256, 256, 0, stream>>>(partw, part2w, WvT, bv, slots,
                                     WihT, bih, WhhT, bhh, W1T, b1, W2T, b2, gf, bff,
                                     (it == 2) ? out : slots);
    }
}

// Round 11
// 667.154 us; speedup vs baseline: 1.3958x; 1.0586x over previous
//
#include <hip/hip_runtime.h>

typedef unsigned short u16;
typedef __bf16 bf16x8 __attribute__((ext_vector_type(8)));
typedef float f32x4 __attribute__((ext_vector_type(4)));
typedef float f32x2 __attribute__((ext_vector_type(2)));

#define DEV static __device__ __forceinline__

DEV u16 f2bf(float f) {
    unsigned int u = __builtin_bit_cast(unsigned int, f);
    u += 0x7FFFu + ((u >> 16) & 1u);
    return (u16)(u >> 16);
}

DEV bf16x8 frag_ld(const u16* p) {  // p must be 16B aligned
    return __builtin_bit_cast(bf16x8, *(const uint4*)p);
}

DEV float sigm(float x) { return 1.f / (1.f + __expf(-x)); }

DEV float blo(unsigned u) { return __builtin_bit_cast(float, u << 16); }
DEV float bhi(unsigned u) { return __builtin_bit_cast(float, u & 0xffff0000u); }
DEV f32x2 bf2(unsigned u) { return (f32x2){ blo(u), bhi(u) }; }

// stash-half [64][256] u16, 16B-unit XOR swizzle by row&7 (u16-index units: <<3)
DEV int sw(int row, int colu16) { return row * 256 + (colu16 ^ ((row & 7) << 3)); }

// global -> LDS direct (width 16B); lds dest must be wave-uniform base + lane*16
DEV void gld16(const u16* g, u16* l) {
    __builtin_amdgcn_global_load_lds(
        (const __attribute__((address_space(1))) unsigned int*)g,
        (__attribute__((address_space(3))) unsigned int*)l, 16, 0, 0);
}

// ---------------- kSetupLN: one-time prep + LN(inputs) in ONE dispatch ----------------
// blocks [0,2048): LN 128 rows each | [2048,2560): slot init | [2560,2818): Wqk fold
// | [2818,3394): 5 weight transposes
__global__ __launch_bounds__(256) void kSetupLN(
    const float* __restrict__ X, const float* __restrict__ gin, const float* __restrict__ bin,
    u16* __restrict__ XN,
    const float* __restrict__ noise, const float* __restrict__ mean,
    const float* __restrict__ logv, float* __restrict__ slots,
    const float* __restrict__ Wq, const float* __restrict__ Wk,
    const float* __restrict__ bq, const float* __restrict__ bk,
    float* __restrict__ Wqk, float* __restrict__ wbc,
    const float* __restrict__ Wv,  float* __restrict__ WvT,
    const float* __restrict__ Wih, float* __restrict__ WihT,
    const float* __restrict__ Whh, float* __restrict__ WhhT,
    const float* __restrict__ W1,  float* __restrict__ W1T,
    const float* __restrict__ W2,  float* __restrict__ W2T)
{
    __shared__ float tile[32][33];
    const int bid = blockIdx.x, t = threadIdx.x;
    if (bid < 2048) {                      // LN(inputs) -> XN bf16
        const int w = t >> 6, lane = t & 63;
        const int c = lane << 2;
        const float4 g4 = *(const float4*)(gin + c);
        const float4 b4 = *(const float4*)(bin + c);
        const size_t r0 = (size_t)bid * 128 + (size_t)w * 32;
        #pragma unroll 4
        for (int i = 0; i < 32; ++i) {
            const float4 x = *(const float4*)(X + (r0 + i) * 256 + c);
            float s1 = x.x + x.y + x.z + x.w;
            float s2 = x.x * x.x + x.y * x.y + x.z * x.z + x.w * x.w;
            #pragma unroll
            for (int o = 32; o > 0; o >>= 1) { s1 += __shfl_xor(s1, o); s2 += __shfl_xor(s2, o); }
            const float mu = s1 * (1.f / 256.f);
            const float rs = rsqrtf(s2 * (1.f / 256.f) - mu * mu + 1e-5f);
            ushort4 pk;
            pk.x = f2bf((x.x - mu) * rs * g4.x + b4.x);
            pk.y = f2bf((x.y - mu) * rs * g4.y + b4.y);
            pk.z = f2bf((x.z - mu) * rs * g4.z + b4.z);
            pk.w = f2bf((x.w - mu) * rs * g4.w + b4.w);
            *(ushort4*)(XN + (r0 + i) * 256 + c) = pk;
        }
        return;
    }
    if (bid < 2560) {                      // slots = mean + exp(logvar)*noise
        const int id = (bid - 2048) * 256 + t;
        const int d = id & 255;
        slots[id] = mean[d] + __expf(logv[d]) * noise[id];
        return;
    }
    if (bid < 2818) {                      // Wqk fold + wbc extras
        const int a = bid - 2560, e = t;
        if (a < 256) {
            float acc = 0.f;
            for (int d = 0; d < 256; ++d) acc += Wq[(size_t)d * 256 + a] * Wk[(size_t)d * 256 + e];
            Wqk[(size_t)a * 256 + e] = acc;
        } else if (a == 256) {
            float acc = 0.f;
            for (int d = 0; d < 256; ++d) acc += bq[d] * Wk[(size_t)d * 256 + e];
            wbc[e] = acc;
        } else {
            float acc = 0.f;
            for (int d = 0; d < 256; ++d) acc += Wq[(size_t)d * 256 + e] * bk[d];
            wbc[256 + e] = acc;
            if (e == 0) {
                float c0 = 0.f;
                for (int d = 0; d < 256; ++d) c0 += bq[d] * bk[d];
                wbc[512] = c0;
            }
        }
        return;
    }
    const int rb = bid - 2818;
    const float* in; float* outp; int R, k;
    if (rb < 64)       { in = Wv;  outp = WvT;  R = 256; k = rb; }
    else if (rb < 256) { in = Wih; outp = WihT; R = 768; k = rb - 64; }
    else if (rb < 448) { in = Whh; outp = WhhT; R = 768; k = rb - 256; }
    else if (rb < 512) { in = W1;  outp = W1T;  R = 256; k = rb - 448; }
    else               { in = W2;  outp = W2T;  R = 256; k = rb - 512; }
    const int bx = k & 7, by = k >> 3;
    const int tx = t & 31, ty = t >> 5;
    const int c0 = bx * 32, r0 = by * 32;
    #pragma unroll
    for (int i = 0; i < 4; ++i)
        tile[ty + i * 8][tx] = in[(size_t)(r0 + ty + i * 8) * 256 + c0 + tx];
    __syncthreads();
    #pragma unroll
    for (int i = 0; i < 4; ++i)
        outp[(size_t)(c0 + ty + i * 8) * R + r0 + tx] = tile[tx][ty + i * 8];
}

// ---------------- kSn: LN(slots) -> qk = SCALE*(sn@Wqk + bqk) bf16; qc ----------------
__global__ __launch_bounds__(256) void kSn(
    const float* __restrict__ slots, const float* __restrict__ gs, const float* __restrict__ bs,
    const float* __restrict__ Wqk, const float* __restrict__ wbc,
    u16* __restrict__ qo, float* __restrict__ qc)
{
    __shared__ float SN[8][256];
    __shared__ float red2[4][8][64];
    const int t = threadIdx.x;
    const int b = blockIdx.y, seg = blockIdx.x;
    const int w = t >> 6, lane = t & 63;
    #pragma unroll
    for (int rr = 0; rr < 2; ++rr) {
        const int r = w * 2 + rr;
        const int c = lane * 4;
        const float4 x = *(const float4*)(slots + ((size_t)b * 8 + r) * 256 + c);
        float s1 = x.x + x.y + x.z + x.w;
        float s2 = x.x * x.x + x.y * x.y + x.z * x.z + x.w * x.w;
        #pragma unroll
        for (int o = 32; o > 0; o >>= 1) { s1 += __shfl_xor(s1, o); s2 += __shfl_xor(s2, o); }
        const float mu = s1 * (1.f / 256.f);
        const float rs = rsqrtf(s2 * (1.f / 256.f) - mu * mu + 1e-5f);
        const float4 g4 = *(const float4*)(gs + c);
        const float4 b4 = *(const float4*)(bs + c);
        SN[r][c + 0] = (x.x - mu) * rs * g4.x + b4.x;
        SN[r][c + 1] = (x.y - mu) * rs * g4.y + b4.y;
        SN[r][c + 2] = (x.z - mu) * rs * g4.z + b4.z;
        SN[r][c + 3] = (x.w - mu) * rs * g4.w + b4.w;
    }
    __syncthreads();
    const int c = seg * 64 + (t & 63);
    const int p = t >> 6;
    float acc[8] = {};
    #pragma unroll 4
    for (int d = p * 64; d < p * 64 + 64; ++d) {
        const float wq = Wqk[(size_t)d * 256 + c];
        #pragma unroll
        for (int r = 0; r < 8; ++r) acc[r] += wq * SN[r][d];
    }
    #pragma unroll
    for (int r = 0; r < 8; ++r) red2[p][r][t & 63] = acc[r];
    __syncthreads();
    const float bb = wbc[c];
    #pragma unroll
    for (int rr = t >> 6; rr < 8; rr += 4) {
        const float s = red2[0][rr][t & 63] + red2[1][rr][t & 63]
                      + red2[2][rr][t & 63] + red2[3][rr][t & 63];
        qo[((size_t)b * 16 + rr) * 256 + c] = f2bf((s + bb) * 0.0625f);
    }
    if (seg == 0) {
        const int r = t >> 5, l = t & 31;
        float a = 0.f;
        #pragma unroll
        for (int d8 = 0; d8 < 8; ++d8) a += SN[r][l * 8 + d8] * wbc[256 + l * 8 + d8];
        #pragma unroll
        for (int o = 16; o > 0; o >>= 1) a += __shfl_xor(a, o);
        if (l == 0) qc[(size_t)b * 8 + r] = 0.0625f * (a + wbc[512]);
    }
}

// ---------------- kF: dots -> softmax -> us, dbuf staging + block-level part reduce ----------
// grid (16 nt of 256 j, 64 b), 256 thr (4 waves). Verified r10 main loop; changes:
// (a) T5 s_setprio(1) around compute; (b) epilogue block-reduces partials in LDS
// (r4-verified usred pattern, stash reused) -> part shrinks to [16][64][8][256].
__global__ __launch_bounds__(256, 3) void kF(
    const u16* __restrict__ Q,        // qk_s [B,16,256] bf16 (rows 8..15 unused)
    const float* __restrict__ qcg,    // [B,8]
    const u16* __restrict__ XN,       // [B,4096,256] bf16
    float* __restrict__ attn_out,
    float* __restrict__ part,         // [16][64][8][256] f32 (per-block partials)
    float* __restrict__ part2,        // [16][64][8]      f32 (attn row-sums)
    int write_attn)
{
    __shared__ __align__(16) u16 stash[2 * 64 * 256];   // 64 KB, 2 halves, XOR-swizzled
    __shared__ __align__(16) float att32[64][8];        // attn f32 [row][slot], wave-private
    const int tid = threadIdx.x;
    const int w = tid >> 6, lane = tid & 63;
    const int quad = lane >> 4, l16 = lane & 15;
    const int dsg = lane & 31, jg = lane >> 5;
    const int qb1 = (quad & 1) << 2;
    const int b = blockIdx.y, nt = blockIdx.x;
    const int j0 = nt << 8;
    const size_t rowbase = (size_t)b * 4096 + j0;
    const int srow = w * 16;                            // this wave's row base in a half

    const u16* qptr = Q + (size_t)b * 16 * 256;
    bf16x8 qfrag[8];
    #pragma unroll
    for (int k0 = 0; k0 < 8; ++k0)
        qfrag[k0] = frag_ld(qptr + l16 * 256 + k0 * 32 + quad * 8);

    float c8[8];
    #pragma unroll
    for (int i = 0; i < 8; ++i) c8[i] = qcg[(size_t)b * 8 + i];

    f32x2 acc2[8][4];
    #pragma unroll
    for (int i = 0; i < 8; ++i)
        #pragma unroll
        for (int k = 0; k < 4; ++k) acc2[i][k] = (f32x2){0.f, 0.f};
    float sacc[4] = {};

    // stage chunk ck's rows (this wave's 16) into stash half h (verbatim r9/r10 mapping)
#define STAGE(ck, h)                                                          \
    {                                                                         \
        const u16* xb = XN + (rowbase + (ck) * 64) * 256;                     \
        u16* dst = stash + (h) * 16384;                                       \
        _Pragma("unroll")                                                     \
        for (int i = 0; i < 8; ++i) {                                         \
            const int il = i * 64 + lane;                                     \
            const int rloc = il >> 5;                                         \
            const int ug = (il & 31) ^ (rloc & 7);                            \
            gld16(xb + (size_t)(srow + rloc) * 256 + ug * 8,                  \
                  dst + ((srow << 5) + il) * 8);                              \
        }                                                                     \
    }

    STAGE(0, 0);
    for (int st = 0; st < 4; ++st) {
        if (st < 3) {
            STAGE(st + 1, (st + 1) & 1);
            asm volatile("s_waitcnt vmcnt(8)" ::: "memory");   // chunk st's loads done
        } else {
            asm volatile("s_waitcnt vmcnt(0)" ::: "memory");   // final drain
        }
        const u16* sh = stash + (st & 1) * 16384;
        __builtin_amdgcn_s_setprio(1);                          // T5: favor compute wave

        // ---- dots: 8 MFMA, B-frags from stash (verbatim r10) ----
        f32x4 dacc = {};
        #pragma unroll
        for (int k0 = 0; k0 < 8; ++k0) {
            const bf16x8 bfr = frag_ld(sh + sw(srow + l16, k0 * 32 + quad * 8));
            dacc = __builtin_amdgcn_mfma_f32_16x16x32_bf16(qfrag[k0], bfr, dacc, 0, 0, 0);
        }
        // ---- softmax over 8 slots for column j = srow + l16 (wave-local) ----
        {
            float v[8];
            #pragma unroll
            for (int r = 0; r < 4; ++r) {
                v[qb1 + r]       = dacc[r];
                v[(qb1 ^ 4) + r] = __shfl_xor(dacc[r], 16);
            }
            #pragma unroll
            for (int i = 0; i < 8; ++i) v[i] += c8[i];
            float m = v[0];
            #pragma unroll
            for (int i = 1; i < 8; ++i) m = fmaxf(m, v[i]);
            float s = 0.f;
            #pragma unroll
            for (int i = 0; i < 8; ++i) { v[i] = __expf(v[i] - m); s += v[i]; }
            const float inv = 1.f / s;
            if (quad < 2) {
                float4 av;
                av.x = v[qb1 + 0] * inv + 1e-8f;
                av.y = v[qb1 + 1] * inv + 1e-8f;
                av.z = v[qb1 + 2] * inv + 1e-8f;
                av.w = v[qb1 + 3] * inv + 1e-8f;
                sacc[0] += av.x; sacc[1] += av.y; sacc[2] += av.z; sacc[3] += av.w;
                *(float4*)&att32[srow + l16][qb1] = av;
                if (write_attn) {
                    const size_t jglob = j0 + st * 64 + srow + l16;
                    attn_out[((size_t)b * 8 + qb1 + 0) * 4096 + jglob] = av.x;
                    attn_out[((size_t)b * 8 + qb1 + 1) * 4096 + jglob] = av.y;
                    attn_out[((size_t)b * 8 + qb1 + 2) * 4096 + jglob] = av.z;
                    attn_out[((size_t)b * 8 + qb1 + 3) * 4096 + jglob] = av.w;
                }
            }
        }
        // ---- us: packed-FMA from the stash (verbatim r10) ----
        #pragma unroll
        for (int jj = 0; jj < 8; ++jj) {
            const int row = srow + jj * 2 + jg;
            const uint4 raw = *(const uint4*)(sh + sw(row, dsg * 8));
            const float4 a0 = *(const float4*)&att32[row][0];
            const float4 a1 = *(const float4*)&att32[row][4];
            f32x2 xf[4];
            xf[0] = bf2(raw.x); xf[1] = bf2(raw.y); xf[2] = bf2(raw.z); xf[3] = bf2(raw.w);
            const float av8[8] = {a0.x, a0.y, a0.z, a0.w, a1.x, a1.y, a1.z, a1.w};
            #pragma unroll
            for (int i = 0; i < 8; ++i) {
                const f32x2 aa = (f32x2){av8[i], av8[i]};
                #pragma unroll
                for (int k = 0; k < 4; ++k)
                    acc2[i][k] = aa * xf[k] + acc2[i][k];
            }
        }
        __builtin_amdgcn_s_setprio(0);
    }
#undef STAGE

    // ---- epilogue: block-level reduction (r4-verified usred pattern) ----
    #pragma unroll
    for (int i = 0; i < 8; ++i)
        #pragma unroll
        for (int k = 0; k < 4; ++k) {
            acc2[i][k][0] += __shfl_xor(acc2[i][k][0], 32);
            acc2[i][k][1] += __shfl_xor(acc2[i][k][1], 32);
        }
    #pragma unroll
    for (int r = 0; r < 4; ++r)
        #pragma unroll
        for (int o = 1; o < 16; o <<= 1) sacc[r] += __shfl_xor(sacc[r], o);

    __syncthreads();                         // main loop done: stash + att32 reusable
    float* usred = (float*)stash;            // [4][8][256] f32 = 32 KB (first stash half)
    float* sred2 = (float*)att32;            // [4][2][4] f32
    if (jg == 0) {
        #pragma unroll
        for (int i = 0; i < 8; ++i) {
            float4 lo, hi;
            lo.x = acc2[i][0][0]; lo.y = acc2[i][0][1]; lo.z = acc2[i][1][0]; lo.w = acc2[i][1][1];
            hi.x = acc2[i][2][0]; hi.y = acc2[i][2][1]; hi.z = acc2[i][3][0]; hi.w = acc2[i][3][1];
            *(float4*)&usred[(w * 8 + i) * 256 + dsg * 8]     = lo;
            *(float4*)&usred[(w * 8 + i) * 256 + dsg * 8 + 4] = hi;
        }
    }
    if (l16 == 0 && quad < 2) {
        #pragma unroll
        for (int r = 0; r < 4; ++r) sred2[(w * 2 + quad) * 4 + r] = sacc[r];
    }
    __syncthreads();
    const size_t pb = ((size_t)nt * 64 + b) * 8;
    #pragma unroll
    for (int i = 0; i < 8; ++i) {
        const float s = usred[(0 * 8 + i) * 256 + tid] + usred[(1 * 8 + i) * 256 + tid]
                      + usred[(2 * 8 + i) * 256 + tid] + usred[(3 * 8 + i) * 256 + tid];
        part[(pb + i) * 256 + tid] = s;
    }
    if (tid < 8) {
        const int q = tid >> 2, r = tid & 3;
        part2[pb + tid] = sred2[(0 * 2 + q) * 4 + r] + sred2[(1 * 2 + q) * 4 + r]
                        + sred2[(2 * 2 + q) * 4 + r] + sred2[(3 * 2 + q) * 4 + r];
    }
}

// ---------------- kB3: US-reduce + Wv GEMV + GRU + LN + MLP, all split-K ----------------
// grid 256 blocks (2 rows each), 256 threads = (kp 0..3) x (c 0..63)
__global__ __launch_bounds__(256) void kB3(
    const float* __restrict__ part, const float* __restrict__ part2,
    const float* __restrict__ WvT, const float* __restrict__ bv,
    const float* __restrict__ sl_in,
    const float* __restrict__ WihT, const float* __restrict__ bih,
    const float* __restrict__ WhhT, const float* __restrict__ bhh,
    const float* __restrict__ W1T, const float* __restrict__ b1,
    const float* __restrict__ W2T, const float* __restrict__ b2,
    const float* __restrict__ gf, const float* __restrict__ bff,
    float* __restrict__ sl_out)
{
    __shared__ float Ul[2][256], Sl[2][256];
    __shared__ float red[2][4][6][256];
    __shared__ float SNl[2][256];
    __shared__ float cw[2][2][4];
    __shared__ float Ssl[2];
    const int t = threadIdx.x;
    const int kp = t >> 6, c = t & 63;
    const int row0 = blockIdx.x * 2;

    #pragma unroll
    for (int r = 0; r < 2; ++r) {
        const int row = row0 + r;
        const int b = row >> 3, s = row & 7;
        float ua0 = 0.f, ua1 = 0.f;
        #pragma unroll
        for (int u = 0; u < 16; u += 2) {
            ua0 += part[(((size_t)u * 64 + b) * 8 + s) * 256 + t];
            ua1 += part[(((size_t)(u + 1) * 64 + b) * 8 + s) * 256 + t];
        }
        Ul[r][t] = ua0 + ua1;
        Sl[r][t] = sl_in[(size_t)row * 256 + t];
    }
    if (t < 2) {
        const int row = row0 + t;
        const int b = row >> 3, s = row & 7;
        float ss = 0.f;
        #pragma unroll
        for (int u = 0; u < 16; ++u) ss += part2[((size_t)u * 64 + b) * 8 + s];
        Ssl[t] = ss;
    }
    __syncthreads();

    {
        float va[2][4] = {};
        #pragma unroll 4
        for (int dd = 0; dd < 64; ++dd) {
            const int d = kp * 64 + dd;
            const float* wr = WvT + (size_t)d * 256;
            const float u0 = Ul[0][d], u1 = Ul[1][d];
            #pragma unroll
            for (int cg = 0; cg < 4; ++cg) {
                const float wv = wr[cg * 64 + c];
                va[0][cg] += wv * u0;
                va[1][cg] += wv * u1;
            }
        }
        #pragma unroll
        for (int r = 0; r < 2; ++r)
            #pragma unroll
            for (int cg = 0; cg < 4; ++cg)
                red[r][kp][0][cg * 64 + c] = va[r][cg];
    }
    __syncthreads();
    const float bvt = bv[t];
    float upd2[2];
    #pragma unroll
    for (int r = 0; r < 2; ++r)
        upd2[r] = red[r][0][0][t] + red[r][1][0][t] + red[r][2][0][t] + red[r][3][0][t]
                + Ssl[r] * bvt;
    __syncthreads();
    #pragma unroll
    for (int r = 0; r < 2; ++r) Ul[r][t] = upd2[r];
    __syncthreads();

    float ga[2][4][6] = {};
    #pragma unroll 2
    for (int dd = 0; dd < 64; ++dd) {
        const int d = kp * 64 + dd;
        const float* wi = WihT + (size_t)d * 768;
        const float* wh = WhhT + (size_t)d * 768;
        const float u0 = Ul[0][d], u1 = Ul[1][d];
        const float s0 = Sl[0][d], s1 = Sl[1][d];
        #pragma unroll
        for (int cg = 0; cg < 4; ++cg) {
            const int t2 = cg * 64 + c;
            const float wa = wi[t2], wb = wi[256 + t2], wc = wi[512 + t2];
            const float wd = wh[t2], we = wh[256 + t2], wf = wh[512 + t2];
            ga[0][cg][0] += wa * u0; ga[0][cg][1] += wb * u0; ga[0][cg][2] += wc * u0;
            ga[0][cg][3] += wd * s0; ga[0][cg][4] += we * s0; ga[0][cg][5] += wf * s0;
            ga[1][cg][0] += wa * u1; ga[1][cg][1] += wb * u1; ga[1][cg][2] += wc * u1;
            ga[1][cg][3] += wd * s1; ga[1][cg][4] += we * s1; ga[1][cg][5] += wf * s1;
        }
    }
    #pragma unroll
    for (int r = 0; r < 2; ++r)
        #pragma unroll
        for (int cg = 0; cg < 4; ++cg)
            #pragma unroll
            for (int g = 0; g < 6; ++g)
                red[r][kp][g][cg * 64 + c] = ga[r][cg][g];
    __syncthreads();

    const float b_ir = bih[t], b_iz = bih[256 + t], b_in = bih[512 + t];
    const float b_hr = bhh[t], b_hz = bhh[256 + t], b_hn = bhh[512 + t];
    float hnew[2];
    #pragma unroll
    for (int r = 0; r < 2; ++r) {
        float s6[6];
        #pragma unroll
        for (int g = 0; g < 6; ++g)
            s6[g] = red[r][0][g][t] + red[r][1][g][t] + red[r][2][g][t] + red[r][3][g][t];
        const float rg = sigm(s6[0] + b_ir + s6[3] + b_hr);
        const float zg = sigm(s6[1] + b_iz + s6[4] + b_hz);
        const float ng = tanhf(s6[2] + b_in + rg * (s6[5] + b_hn));
        hnew[r] = (1.f - zg) * ng + zg * Sl[r][t];
    }
    #pragma unroll
    for (int r = 0; r < 2; ++r) {
        float s1 = hnew[r], s2 = hnew[r] * hnew[r];
        #pragma unroll
        for (int o = 32; o > 0; o >>= 1) { s1 += __shfl_xor(s1, o); s2 += __shfl_xor(s2, o); }
        if (c == 0) { cw[r][0][kp] = s1; cw[r][1][kp] = s2; }
    }
    __syncthreads();
    const float gft = gf[t], bfft = bff[t];
    #pragma unroll
    for (int r = 0; r < 2; ++r) {
        const float s1 = cw[r][0][0] + cw[r][0][1] + cw[r][0][2] + cw[r][0][3];
        const float s2 = cw[r][1][0] + cw[r][1][1] + cw[r][1][2] + cw[r][1][3];
        const float mu = s1 * (1.f / 256.f);
        const float rs = rsqrtf(s2 * (1.f / 256.f) - mu * mu + 1e-5f);
        SNl[r][t] = (hnew[r] - mu) * rs * gft + bfft;
    }
    __syncthreads();

    {
        float m1[2][4] = {};
        #pragma unroll 4
        for (int dd = 0; dd < 64; ++dd) {
            const int d = kp * 64 + dd;
            const float* wr = W1T + (size_t)d * 256;
            const float n0 = SNl[0][d], n1 = SNl[1][d];
            #pragma unroll
            for (int cg = 0; cg < 4; ++cg) {
                const float wv = wr[cg * 64 + c];
                m1[0][cg] += wv * n0;
                m1[1][cg] += wv * n1;
            }
        }
        #pragma unroll
        for (int r = 0; r < 2; ++r)
            #pragma unroll
            for (int cg = 0; cg < 4; ++cg)
                red[r][kp][0][cg * 64 + c] = m1[r][cg];
    }
    __syncthreads();
    const float b1t = b1[t];
    float h1v[2];
    #pragma unroll
    for (int r = 0; r < 2; ++r)
        h1v[r] = fmaxf(red[r][0][0][t] + red[r][1][0][t] + red[r][2][0][t] + red[r][3][0][t]
                       + b1t, 0.f);
    __syncthreads();
    #pragma unroll
    for (int r = 0; r < 2; ++r) SNl[r][t] = h1v[r];
    __syncthreads();
    {
        float m2[2][4] = {};
        #pragma unroll 4
        for (int dd = 0; dd < 64; ++dd) {
            const int d = kp * 64 + dd;
            const float* wr = W2T + (size_t)d * 256;
            const float x0 = SNl[0][d], x1 = SNl[1][d];
            #pragma unroll
            for (int cg = 0; cg < 4; ++cg) {
                const float wv = wr[cg * 64 + c];
                m2[0][cg] += wv * x0;
                m2[1][cg] += wv * x1;
            }
        }
        #pragma unroll
        for (int r = 0; r < 2; ++r)
            #pragma unroll
            for (int cg = 0; cg < 4; ++cg)
                red[r][kp][1][cg * 64 + c] = m2[r][cg];
    }
    __syncthreads();
    const float b2t = b2[t];
    #pragma unroll
    for (int r = 0; r < 2; ++r) {
        const float o = red[r][0][1][t] + red[r][1][1][t] + red[r][2][1][t] + red[r][3][1][t];
        sl_out[(size_t)(row0 + r) * 256 + t] = hnew[r] + o + b2t;
    }
}

// ---------------- launch ----------------
extern "C" void kernel_launch(void* const* d_in, const int* in_sizes, int n_in,
                              void* d_out, int out_size, void* d_ws, size_t ws_size,
                              hipStream_t stream) {
    const float* inputs = (const float*)d_in[0];
    const float* noise  = (const float*)d_in[1];
    const float* smean  = (const float*)d_in[2];
    const float* slogv  = (const float*)d_in[3];
    const float* Wq  = (const float*)d_in[4];
    const float* bq  = (const float*)d_in[5];
    const float* Wk  = (const float*)d_in[6];
    const float* bk  = (const float*)d_in[7];
    const float* Wv  = (const float*)d_in[8];
    const float* bv  = (const float*)d_in[9];
    const float* Wih = (const float*)d_in[10];
    const float* bih = (const float*)d_in[11];
    const float* Whh = (const float*)d_in[12];
    const float* bhh = (const float*)d_in[13];
    const float* W1  = (const float*)d_in[14];
    const float* b1  = (const float*)d_in[15];
    const float* W2  = (const float*)d_in[16];
    const float* b2  = (const float*)d_in[17];
    const float* gin = (const float*)d_in[18];
    const float* bin = (const float*)d_in[19];
    const float* gs  = (const float*)d_in[20];
    const float* bs  = (const float*)d_in[21];
    const float* gf  = (const float*)d_in[22];
    const float* bff = (const float*)d_in[23];

    // workspace layout (~146.4 MB)
    char* ws = (char*)d_ws;
    u16*  XNw    = (u16*)(ws);                          // 134,217,728  LN(x) bf16 [B,N,D]
    u16*  qw     = (u16*)(ws + 134217728ull);           //     524,288
    float* slots = (float*)(ws + 134742016ull);         //     524,288
    float* Wqkw  = (float*)(ws + 135266304ull);         //     262,144
    float* wbc   = (float*)(ws + 135528448ull);         //       4,096
    float* qcw   = (float*)(ws + 135532544ull);         //       4,096
    float* WvT   = (float*)(ws + 135536640ull);         //     262,144
    float* WihT  = (float*)(ws + 135798784ull);         //     786,432
    float* WhhT  = (float*)(ws + 136585216ull);         //     786,432
    float* W1T   = (float*)(ws + 137371648ull);         //     262,144
    float* W2T   = (float*)(ws + 137633792ull);         //     262,144
    float* partw = (float*)(ws + 137895936ull);         //   8,388,608  [16][64][8][256]
    float* part2w= (float*)(ws + 146284544ull);         //      32,768  [16][64][8]

    float* out = (float*)d_out;
    float* attn_out = out + 131072;                     // [B,S,N] after slots [B,S,D]

    kSetupLN<<<3394, 256, 0, stream>>>(inputs, gin, bin, XNw,
                                       noise, smean, slogv, slots,
                                       Wq, Wk, bq, bk, Wqkw, wbc,
                                       Wv, WvT, Wih, WihT, Whh, WhhT, W1, W1T, W2, W2T);
    for (int it = 0; it < 3; ++it) {
        kSn<<<dim3(4, 64), 256, 0, stream>>>(slots, gs, bs, Wqkw, wbc, qw, qcw);
        kF<<<dim3(16, 64), 256, 0, stream>>>(qw, qcw, XNw, attn_out, partw, part2w, it == 2);
        kB3<<<256, 256, 0, stream>>>(partw, part2w, WvT, bv, slots,
                                     WihT, bih, WhhT, bhh, W1T, b1, W2T, b2, gf, bff,
                                     (it == 2) ? out : slots);
    }
}